// Round 5
// baseline (2778.361 us; speedup 1.0000x reference)
//
#include <hip/hip_runtime.h>
#include <cstdint>
#include <cstddef>

#define DD 12
#define NNODE 32768
#define LTOK 3
#define KCH 4
#define HD 128
#define NC_STEP 896
#define KD_STEP 640
#define NC_EMB 128
#define KD_EMB 384
#define NCP 1024   // padded output cols for the step GEMM

typedef unsigned short u16;
typedef __attribute__((ext_vector_type(8))) __bf16 bf16x8;
typedef __attribute__((ext_vector_type(4))) float f32x4;

__device__ __forceinline__ float bf2f(unsigned int u) {
  union { unsigned int i; float f; } v; v.i = (u & 0xffffu) << 16; return v.f;
}
__device__ __forceinline__ u16 f2bf(float f) {
  union { float f; unsigned int i; } v; v.f = f;
  unsigned int x = v.i;
  return (u16)((x + 0x7fffu + ((x >> 16) & 1u)) >> 16);
}
__device__ __forceinline__ float sigm(float x) { return 1.f / (1.f + __expf(-x)); }
__device__ __forceinline__ float tanh_fast(float x) { return 1.f - 2.f / (1.f + __expf(2.f * x)); }
__device__ __forceinline__ void async16(const void* g, void* l) {
  __builtin_amdgcn_global_load_lds((const __attribute__((address_space(1))) unsigned int*)g,
                                   (__attribute__((address_space(3))) unsigned int*)l, 16, 0, 0);
}

// ---------------------------------------------------------------------------
// R13 step GEMM (resubmit after infra failure): pre[32768,896] =
// A[32768,640] @ Ubig[1024(pad),640]^T + bias.
// R3 post-mortem: tile critical path was LDS-port-bound (A+B reads 128 KB +
// 48 KB gload-writes per tile vs MFMA ~310 cyc). Fix = traffic, not sync:
//  - B (Ubig, 1.25 MB, L2-resident) is NO LONGER staged in LDS: fragments
//    load straight to VGPRs from L2 (separate VMEM pipe, overlaps LDS pipe).
//  - BM=256 x BN=256 (cols padded to 1024; masked epilogue), 8 waves of
//    128x64 (2M x 4N). Per-output LDS traffic: 176 -> 80 KB (-55%).
//  - Grid 512 blocks = exactly 2 CU-rounds (R3's 896 grid had a 3.5-round
//    50%-tail). XCD chunk swizzle 512 = 8*64, col-tile fastest (A-panel
//    reused 4x within an XCD's L2 - R2-proven FETCH win).
// Sync = R3's proven rhythm: ONE raw s_barrier per K-tile, prefetch depth 2,
// never drain-to-0. vmcnt ledger (order PINNED by sched_barrier(0)):
//   per tile t: [B(t) 8 loads] [stageA(t+2) 4 async16] [ds_read+MFMA] ...
//   compiler's wait before B(t)'s use counts 4 outstanding (= A(t+2)) ->
//   vmcnt(4): drains A(t+1) (and B(t)), leaves A(t+2) in flight. Explicit
//   belt vmcnt(4) before the barrier restates the invariant.
// Race-freedom:
//   RAW A(t): drained at tile t-1 (B(t-1)-use wait, FIFO: A(t) older) +
//             barrier(t-1) for cross-wave visibility.
//   WAR: stageA(t+2) -> buf (t+2)%3, readers were tile t-1 (done before
//        barrier(t-1) which precedes these issues).
// LDS rows UNPADDED 128 B (global_load_lds lands base+lane*16); XOR swizzle
// slot s of row r holds global chunk s^(r&7); fragment read slot
// (ks*4+q)^(L&7) -> conflict-free (0 conflicts R0-R3).
// ---------------------------------------------------------------------------
#define BM 256
#define BN 256
#define BK 64

__global__ __launch_bounds__(512, 2) void gemm8_k(
    const u16* __restrict__ Abf, const u16* __restrict__ Tbf,
    const int* __restrict__ gidx, const u16* __restrict__ B,
    const float* __restrict__ bias, u16* __restrict__ outb,
    const u16* __restrict__ zbuf)
{
  __shared__ u16 As[3][BM * BK];   // 3 x 32 KB = 96 KB
  const int t = threadIdx.x;
  const int w = t >> 6;            // 0..7
  const int L = t & 63;
  const int q = L >> 4;
  const int lrow8 = L >> 3;        // row within 8-row slab
  const int sub = L & 7;           // 16B landing slot
  const int swz = sub ^ lrow8;     // global chunk this lane fetches

  // bijective chunked XCD swizzle: 512 = 8 * 64; col-tile fastest in chunk
  const int bid = blockIdx.x;
  const int wg = (bid & 7) * 64 + (bid >> 3);
  const int rt = wg >> 2;          // 0..127
  const int ct = wg & 3;           // 0..3
  const int row0 = rt * BM;
  const int col0 = ct * BN;

  const int wm = w >> 2;           // 0..1 : 128-row group
  const int wn = w & 3;            // 0..3 : 64-col group
  const int mrow = wm * 128;
  const int ncol = wn * 64;

  f32x4 acc[8][4];
#pragma unroll
  for (int a = 0; a < 8; ++a)
#pragma unroll
    for (int b = 0; b < 4; ++b)
      acc[a][b] = f32x4{0.f, 0.f, 0.f, 0.f};

  // gather indices for this wave's 4 A-slabs (rows row0 + w*32 + jj*8 + lrow8)
  int4 cidx[4];
#pragma unroll
  for (int jj = 0; jj < 4; ++jj)
    cidx[jj] = *(const int4*)&gidx[(row0 + w * 32 + jj * 8 + lrow8) * KCH];

  // stage A k-chunk [k0,k0+64) into LDS buffer sel (4 async16 per wave).
  auto stageA = [&](const int k0, const int sel) {
#pragma unroll
    for (int jj = 0; jj < 4; ++jj) {
      const int rbase = w * 32 + jj * 8;
      const u16* src;
      if (k0 < 4 * HD) {
        const int id = ((const int*)&cidx[jj])[k0 >> 7];
        const u16* base = (id >= 1) ? (Abf + (size_t)(id - 1) * HD) : zbuf;
        src = base + (k0 & 127) + swz * 8;
      } else {
        src = Tbf + (size_t)(row0 + rbase + lrow8) * HD + (k0 - 4 * HD) + swz * 8;
      }
      async16(src, &As[sel][rbase * BK]);
    }
  };

  // prologue: stage tiles 0,1; wait tile 0 only (leave tile 1 in flight)
  stageA(0, 0);
  stageA(64, 1);
  asm volatile("s_waitcnt vmcnt(4)" ::: "memory");
  __builtin_amdgcn_sched_barrier(0);
  __builtin_amdgcn_s_barrier();
  __builtin_amdgcn_sched_barrier(0);

  constexpr int NT = KD_STEP / BK;   // 10
#pragma unroll
  for (int tt = 0; tt < NT; ++tt) {
    const int rd = tt % 3;

    // B fragments straight from L2 (issued FIRST - FIFO ledger anchor)
    bf16x8 bfv[2][4];
#pragma unroll
    for (int ks = 0; ks < 2; ++ks)
#pragma unroll
      for (int nt = 0; nt < 4; ++nt) {
        const int col = col0 + ncol + nt * 16 + (L & 15);
        bfv[ks][nt] = *(const bf16x8*)&B[(size_t)col * KD_STEP + tt * 64 + (ks * 4 + q) * 8];
      }
    __builtin_amdgcn_sched_barrier(0);
    // prefetch A two tiles ahead (AFTER B loads - keeps vmcnt FIFO ledger)
    if (tt + 2 < NT) stageA((tt + 2) * 64, (tt + 2) % 3);
    __builtin_amdgcn_sched_barrier(0);

#pragma unroll
    for (int ks = 0; ks < 2; ++ks) {
      bf16x8 af[8];
#pragma unroll
      for (int mt = 0; mt < 8; ++mt)
        af[mt] = *(const bf16x8*)&As[rd][(mrow + mt * 16 + (L & 15)) * BK +
                                        (((ks * 4 + q) ^ (L & 7)) * 8)];
      __builtin_amdgcn_s_setprio(1);
#pragma unroll
      for (int mt = 0; mt < 8; ++mt)
#pragma unroll
        for (int nt = 0; nt < 4; ++nt)
          acc[mt][nt] = __builtin_amdgcn_mfma_f32_16x16x32_bf16(
              af[mt], bfv[ks][nt], acc[mt][nt], 0, 0, 0);
      __builtin_amdgcn_s_setprio(0);
    }

    // tile-end: belt vmcnt (leaves A(t+2) in flight) + ONE barrier
    if (tt < NT - 1) {
      if (tt + 2 < NT) asm volatile("s_waitcnt vmcnt(4)" ::: "memory");
      else             asm volatile("s_waitcnt vmcnt(0)" ::: "memory");
      __builtin_amdgcn_sched_barrier(0);
      __builtin_amdgcn_s_barrier();
      __builtin_amdgcn_sched_barrier(0);
    }
  }

  // epilogue: C/D layout col=lane&15, row=(lane>>4)*4+i ; mask col<896
#pragma unroll
  for (int nt = 0; nt < 4; ++nt) {
    const int col = col0 + ncol + nt * 16 + (L & 15);
    if (col < NC_STEP) {
      const float bb = bias[col];
#pragma unroll
      for (int mt = 0; mt < 8; ++mt) {
#pragma unroll
        for (int i = 0; i < 4; ++i) {
          const int row = row0 + mrow + mt * 16 + q * 4 + i;
          outb[(size_t)row * NC_STEP + col] = f2bf(acc[mt][nt][i] + bb);
        }
      }
    }
  }
}

// ---------------------------------------------------------------------------
// Embed GEMM (R0-proven single-buffer structure):
// tslice[f32] & tbf[bf16] = gather(Ebf, tokens) @ Lbf^T + lin_b
// ---------------------------------------------------------------------------
__global__ __launch_bounds__(256) void gemm_emb_k(
    const u16* __restrict__ Ebf, const int* __restrict__ tokd,
    const u16* __restrict__ Lbf, const float* __restrict__ bias,
    float* __restrict__ outf, u16* __restrict__ outb)
{
  __shared__ u16 As[128 * 64];
  __shared__ u16 Bs[128 * 64];
  const int t = threadIdx.x;
  const int w = t >> 6;
  const int L = t & 63;
  const int q = L >> 4;
  const int lrow8 = L >> 3;
  const int sub = L & 7;
  const int swz = sub ^ lrow8;
  const int row0 = blockIdx.x * 128;

  f32x4 acc[4][4];
#pragma unroll
  for (int a = 0; a < 4; ++a)
#pragma unroll
    for (int b = 0; b < 4; ++b)
      acc[a][b] = f32x4{0.f, 0.f, 0.f, 0.f};

  const int mrow = (w & 1) * 64;
  const int ncol = (w >> 1) * 64;

  int4 cidx[4];
#pragma unroll
  for (int jj = 0; jj < 4; ++jj) {
    const int rit = w * 32 + jj * 8 + lrow8;
    cidx[jj].x = tokd[(row0 + rit) * LTOK + 0];
    cidx[jj].y = tokd[(row0 + rit) * LTOK + 1];
    cidx[jj].z = tokd[(row0 + rit) * LTOK + 2];
    cidx[jj].w = 0;
  }

#pragma unroll
  for (int k0 = 0; k0 < KD_EMB; k0 += 64) {
    __syncthreads();
#pragma unroll
    for (int jj = 0; jj < 4; ++jj) {
      const int id = ((const int*)&cidx[jj])[k0 >> 7];
      const u16* base = Ebf + (size_t)id * HD;
      const int rit = w * 32 + jj * 8 + lrow8;
      async16(base + (k0 & 127) + swz * 8, &As[(w * 32 + jj * 8) * 64]);
      async16(Lbf + (size_t)rit * KD_EMB + k0 + swz * 8, &Bs[(w * 32 + jj * 8) * 64]);
    }
    __syncthreads();
#pragma unroll
    for (int ks = 0; ks < 2; ++ks) {
      bf16x8 af[4], bfr[4];
      const int pc = ((ks * 4 + q) ^ (L & 7)) * 8;
#pragma unroll
      for (int mt = 0; mt < 4; ++mt)
        af[mt] = *(const bf16x8*)&As[(mrow + mt * 16 + (L & 15)) * 64 + pc];
#pragma unroll
      for (int nt = 0; nt < 4; ++nt)
        bfr[nt] = *(const bf16x8*)&Bs[(ncol + nt * 16 + (L & 15)) * 64 + pc];
#pragma unroll
      for (int mt = 0; mt < 4; ++mt)
#pragma unroll
        for (int nt = 0; nt < 4; ++nt)
          acc[mt][nt] = __builtin_amdgcn_mfma_f32_16x16x32_bf16(af[mt], bfr[nt], acc[mt][nt], 0, 0, 0);
    }
  }

#pragma unroll
  for (int nt = 0; nt < 4; ++nt) {
    const int col = ncol + nt * 16 + (L & 15);
    const float bb = bias[col];
#pragma unroll
    for (int mt = 0; mt < 4; ++mt) {
#pragma unroll
      for (int i = 0; i < 4; ++i) {
        const int row = row0 + mrow + mt * 16 + q * 4 + i;
        const float v = acc[mt][nt][i] + bb;
        outf[(size_t)row * NC_EMB + col] = v;
        outb[(size_t)row * NC_EMB + col] = f2bf(v);
      }
    }
  }
}

// ---------------------------------------------------------------------------
// LSTM cell: f = sum_k sig(pre_fk)*c_k ; gates ; c (f32), h (bf16),
// t += h (f32) and bf16 shadow tbf.
// ---------------------------------------------------------------------------
__global__ __launch_bounds__(256) void cell_k(
    const u16* __restrict__ pre, const int* __restrict__ idxs,
    const float* __restrict__ c_prev, float* __restrict__ c_cur,
    u16* __restrict__ h_cur, float* __restrict__ t_io, u16* __restrict__ tbf)
{
  const int g = blockIdx.x * 256 + threadIdx.x;
  const int r = g >> 7;
  const int j = g & 127;
  const u16* pr = pre + (size_t)r * NC_STEP;
  float f = 0.f;
#pragma unroll
  for (int k = 0; k < KCH; ++k) {
    const int id = idxs[r * KCH + k];
    const float cg = (id >= 1) ? c_prev[(size_t)(id - 1) * HD + j] : 0.f;
    f += sigm(bf2f(pr[k * HD + j])) * cg;
  }
  const float iv = sigm(bf2f(pr[4 * HD + j]));
  const float uv = tanh_fast(bf2f(pr[5 * HD + j]));
  const float ov = sigm(bf2f(pr[6 * HD + j]));
  const float cn = iv * uv + f;
  const float hv = ov * tanh_fast(cn);
  c_cur[g] = cn;
  h_cur[g] = f2bf(hv);
  const float tn = t_io[g] + hv;
  t_io[g] = tn;
  tbf[g] = f2bf(tn);
}

__global__ __launch_bounds__(256) void conv_k(const float* __restrict__ src,
                                              u16* __restrict__ dst, int n4)
{
  const int g = blockIdx.x * 256 + threadIdx.x;
  if (g < n4) {
    float4 v = ((const float4*)src)[g];
    ((ushort4*)dst)[g] = make_ushort4(f2bf(v.x), f2bf(v.y), f2bf(v.z), f2bf(v.w));
  }
}

// Build U_big[l][1024(pad)][640] (bf16) = [Uf;Uiuo | W_w(mapped)] + fused
// f32 biases. Rows 896..1023 stay zero (memset by launcher).
__global__ __launch_bounds__(256) void prep_k(
    const float* __restrict__ Uf_w, const float* __restrict__ Uf_b,
    const float* __restrict__ Uiuo_w, const float* __restrict__ Uiuo_b,
    const float* __restrict__ W_w, const float* __restrict__ W_b,
    u16* __restrict__ Ubig, float* __restrict__ biasbig)
{
  const int l = blockIdx.y;
  const int e = blockIdx.x * 256 + threadIdx.x;
  const int c = e / KD_STEP;
  const int k = e % KD_STEP;
  float v;
  if (k < 512) {
    v = (c < 512) ? Uf_w[((size_t)l * 512 + c) * 512 + k]
                  : Uiuo_w[((size_t)l * 384 + (c - 512)) * 512 + k];
  } else {
    const int q = k - 512;
    const int wr = (c < 512) ? (c & 127) : (128 + (c - 512));
    v = W_w[((size_t)l * 512 + wr) * 128 + q];
  }
  Ubig[((size_t)l * NCP + c) * 640 + k] = f2bf(v);
  if (e < 896) {
    const float b = (e < 512)
        ? (Uf_b[l * 512 + e] + W_b[l * 512 + (e & 127)])
        : (Uiuo_b[l * 384 + (e - 512)] + W_b[l * 512 + 128 + (e - 512)]);
    biasbig[l * 896 + e] = b;
  }
}

// Output (FLOAT32): hx = tile(t_final,2), cx = tile(c_final,2).
__global__ __launch_bounds__(256) void fin_k(
    const float* __restrict__ t_fin, const float* __restrict__ c_fin,
    float* __restrict__ out)
{
  const size_t NH = (size_t)NNODE * HD;
  const size_t g = (size_t)blockIdx.x * 256 + threadIdx.x;
  const float h = t_fin[g];
  const float c = c_fin[g];
  out[g] = h;
  out[NH + g] = h;
  out[2 * NH + g] = c;
  out[3 * NH + g] = c;
}

extern "C" void kernel_launch(void* const* d_in, const int* in_sizes, int n_in,
                              void* d_out, int out_size, void* d_ws, size_t ws_size,
                              hipStream_t stream)
{
  (void)in_sizes; (void)n_in; (void)out_size; (void)ws_size;
  const int*   tokens  = (const int*)d_in[0];
  const int*   indices = (const int*)d_in[1];
  const float* E       = (const float*)d_in[2];
  const float* lin_w   = (const float*)d_in[3];
  const float* lin_b   = (const float*)d_in[4];
  const float* Uf_w    = (const float*)d_in[5];
  const float* Uf_b    = (const float*)d_in[6];
  const float* Uiuo_w  = (const float*)d_in[7];
  const float* Uiuo_b  = (const float*)d_in[8];
  const float* W_w     = (const float*)d_in[9];
  const float* W_b     = (const float*)d_in[10];
  float* out = (float*)d_out;   // FLOAT32 output (R8-proven)

  const size_t NH = (size_t)NNODE * HD;

  char* ws = (char*)d_ws;
  size_t off = 0;
  auto alloc = [&](size_t bytes) -> void* {
    void* p = ws + off;
    off = (off + bytes + 255) & ~(size_t)255;
    return p;
  };
  u16*   Ubig    = (u16*)alloc((size_t)2 * NCP * 640 * 2);
  float* biasbig = (float*)alloc(2 * 896 * 4);
  u16*   Ebf     = (u16*)alloc((size_t)50000 * HD * 2);
  u16*   Lbf     = (u16*)alloc((size_t)HD * KD_EMB * 2);
  float* tslice  = (float*)alloc(NH * 4);
  u16*   tbf     = (u16*)alloc(NH * 2);
  u16*   h0a     = (u16*)alloc(NH * 2);
  u16*   h0b     = (u16*)alloc(NH * 2);
  u16*   h1a     = (u16*)alloc(NH * 2);
  u16*   h1b     = (u16*)alloc(NH * 2);
  float* c0a     = (float*)alloc(NH * 4);
  float* c0b     = (float*)alloc(NH * 4);
  float* c1a     = (float*)alloc(NH * 4);
  float* c1b     = (float*)alloc(NH * 4);
  u16*   pre     = (u16*)alloc((size_t)NNODE * NC_STEP * 2);
  u16*   zbuf    = (u16*)alloc(512);

  u16*   h0[2] = {h0a, h0b};
  u16*   h1[2] = {h1a, h1b};
  float* c0[2] = {c0a, c0b};
  float* c1[2] = {c1a, c1b};

  hipMemsetAsync(zbuf, 0, 512, stream);
  hipMemsetAsync(Ubig, 0, (size_t)2 * NCP * 640 * 2, stream);
  hipMemsetAsync(h0[0], 0, NH * 2, stream);
  hipMemsetAsync(h1[0], 0, NH * 2, stream);
  hipMemsetAsync(c0[0], 0, NH * 4, stream);
  hipMemsetAsync(c1[0], 0, NH * 4, stream);
  prep_k<<<dim3(2240, 2), 256, 0, stream>>>(Uf_w, Uf_b, Uiuo_w, Uiuo_b, W_w, W_b,
                                            Ubig, biasbig);
  conv_k<<<dim3((50000 * HD / 4 + 255) / 256), 256, 0, stream>>>(E, Ebf, 50000 * HD / 4);
  conv_k<<<dim3((HD * KD_EMB / 4 + 255) / 256), 256, 0, stream>>>(lin_w, Lbf, HD * KD_EMB / 4);

  for (int d = 0; d < DD; ++d) {
    const int ri = d & 1, wi = (d + 1) & 1;
    const int* idxd = indices + (size_t)d * NNODE * KCH;
    const int* tokd = tokens + (size_t)d * NNODE * LTOK;

    // tslice (f32) + tbf (bf16) = gather(Ebf, tokens[d]) @ Lbf^T + lin_b
    gemm_emb_k<<<dim3(NNODE / 128), 256, 0, stream>>>(
        Ebf, tokd, Lbf, lin_b, tslice, tbf);

    for (int l = 0; l < 2; ++l) {
      const u16*   hp = (l == 0) ? h0[ri] : h1[ri];
      u16*         hc = (l == 0) ? h0[wi] : h1[wi];
      const float* cp = (l == 0) ? c0[ri] : c1[ri];
      float*       cc = (l == 0) ? c0[wi] : c1[wi];
      const u16* Ul = Ubig + (size_t)l * NCP * 640;
      const float* bl = biasbig + l * 896;
      gemm8_k<<<dim3((NNODE / BM) * (NCP / BN)), 512, 0, stream>>>(
          hp, tbf, idxd, Ul, bl, pre, zbuf);
      cell_k<<<dim3((int)(NH / 256)), 256, 0, stream>>>(
          pre, idxd, cp, cc, hc, tslice, tbf);
    }
  }
  // after d=11: tslice = t_final, c1[0] = c_final
  fin_k<<<dim3((int)(NH / 256)), 256, 0, stream>>>(tslice, c1[0], out);
}

// Round 6
// 2151.719 us; speedup vs baseline: 1.2912x; 1.2912x over previous
//
#include <hip/hip_runtime.h>
#include <cstdint>
#include <cstddef>

#define DD 12
#define NNODE 32768
#define LTOK 3
#define KCH 4
#define HD 128
#define NC_STEP 896
#define KD_STEP 640
#define NC_EMB 128
#define KD_EMB 384

typedef unsigned short u16;
typedef __attribute__((ext_vector_type(8))) __bf16 bf16x8;
typedef __attribute__((ext_vector_type(4))) float f32x4;

__device__ __forceinline__ float bf2f(unsigned int u) {
  union { unsigned int i; float f; } v; v.i = (u & 0xffffu) << 16; return v.f;
}
__device__ __forceinline__ u16 f2bf(float f) {
  union { float f; unsigned int i; } v; v.f = f;
  unsigned int x = v.i;
  return (u16)((x + 0x7fffu + ((x >> 16) & 1u)) >> 16);
}
__device__ __forceinline__ float sigm(float x) { return 1.f / (1.f + __expf(-x)); }
__device__ __forceinline__ float tanh_fast(float x) { return 1.f - 2.f / (1.f + __expf(2.f * x)); }
__device__ __forceinline__ void async16(const void* g, void* l) {
  __builtin_amdgcn_global_load_lds((const __attribute__((address_space(1))) unsigned int*)g,
                                   (__attribute__((address_space(3))) unsigned int*)l, 16, 0, 0);
}

// ---------------------------------------------------------------------------
// R14 step GEMM: pre[32768,896] = A[32768,640] @ Ubig[896,640]^T + bias.
// R5 post-mortem: B-direct-from-L2 FAILED (latency exposed at 1 block/CU,
// MfmaUtil 20, dur 82.8). Revert to R3's A+B-in-LDS structure (61.7 us,
// best measured) and change ONE parameter: BK 64->32 so the 3 buffers fit
// in 72 KB -> 2 blocks/CU. This restores the cross-block TLP that made R0
// work (barrier convoys of block A hide under block B's compute) while
// keeping R3's counted-vmcnt depth-2 rhythm (no drain-to-0 mid-loop).
// BM=256 x BN=128, BK=32, 512 thr / 8 waves (4M x 2N -> per-wave 64x64).
// Per K-tile per wave: 3 async16 stage (2 A + 1 B, for tile t+2),
// 8 ds_read_b128 frags, 16 MFMA, belt vmcnt(3), ONE raw s_barrier.
// Ledger: S(t+1) issued at tile t-1; end-of-tile-t vmcnt(3) drains S(t+1)
// (FIFO: leaves the 3 just-issued S(t+2)); barrier gives cross-wave
// visibility. WAR: S(t+2) targets buf[(t+2)%3] whose readers (tile t-1)
// finished before barrier t-1.
// LDS rows 64 B (BK=32), UNPADDED (global_load_lds lands base+lane*16).
// XOR swizzle for 64B rows: phys 16B chunk s of row r holds global chunk
// s^(r&3) (stage lane L: row=L>>2, slot=L&3, global chunk=(L&3)^((L>>2)&3));
// frag read wants global chunk q=L>>4 of row (..+(L&15)) -> phys chunk
// (L>>4)^(L&3); bank check: <=2-way aliasing (free, m136).
// Grid: 1-D 896 = 8*112 bijective XCD chunk swizzle, col-tile fastest
// (R2-proven A-panel L2 reuse: FETCH 88.8 -> 36 MB).
// __launch_bounds__(512,4): 4 waves/SIMD -> VGPR capped 128 (R3 used 88).
// ---------------------------------------------------------------------------
#define BM 256
#define BN 128
#define BK 32

__global__ __launch_bounds__(512, 4) void gemm8_k(
    const u16* __restrict__ Abf, const u16* __restrict__ Tbf,
    const int* __restrict__ gidx, const u16* __restrict__ B,
    const float* __restrict__ bias, u16* __restrict__ outb,
    const u16* __restrict__ zbuf)
{
  __shared__ u16 As[3][BM * BK];   // 3 x 16 KB
  __shared__ u16 Bs[3][BN * BK];   // 3 x 8 KB
  const int t = threadIdx.x;
  const int w = t >> 6;            // 0..7
  const int L = t & 63;
  const int q = L >> 4;            // 0..3 : k-chunk this lane's MFMA frag uses
  const int r16 = L >> 2;          // 0..15 : row within 16-row stage slab
  const int sub = L & 3;           // 16B landing slot within 64B row
  const int swz = sub ^ (r16 & 3); // global chunk this lane fetches

  // bijective chunked XCD swizzle: 896 = 8 * 112; col-tile fastest in chunk
  const int bid = blockIdx.x;
  const int wg = (bid & 7) * 112 + (bid >> 3);
  const int rt = wg / 7;
  const int ct = wg - rt * 7;
  const int row0 = rt * BM;
  const int col0 = ct * BN;

  const int wm = w >> 1;           // 0..3 : 64-row group
  const int wn = w & 1;            // 0..1 : 64-col group
  const int mrow = wm * 64;
  const int ncol = wn * 64;

  f32x4 acc[4][4];
#pragma unroll
  for (int a = 0; a < 4; ++a)
#pragma unroll
    for (int b = 0; b < 4; ++b)
      acc[a][b] = f32x4{0.f, 0.f, 0.f, 0.f};

  // gather indices: wave stages A rows w*32 + j*16 + r16, j=0,1
  int4 cidx[2];
#pragma unroll
  for (int j = 0; j < 2; ++j)
    cidx[j] = *(const int4*)&gidx[(row0 + w * 32 + j * 16 + r16) * KCH];

  // stage k-chunk [k0,k0+32) of tile into buffer sel: 2 A instrs + 1 B instr
  auto stageAll = [&](const int k0, const int sel) {
#pragma unroll
    for (int j = 0; j < 2; ++j) {
      const int rbase = w * 32 + j * 16;     // 16-row slab
      const u16* src;
      if (k0 < 4 * HD) {
        const int id = ((const int*)&cidx[j])[k0 >> 7];
        const u16* base = (id >= 1) ? (Abf + (size_t)(id - 1) * HD) : zbuf;
        src = base + (k0 & 127) + swz * 8;
      } else {
        src = Tbf + (size_t)(row0 + rbase + r16) * HD + (k0 - 4 * HD) + swz * 8;
      }
      async16(src, &As[sel][rbase * BK]);
    }
    const int rb = w * 16;                    // B: 16 rows per wave
    async16(B + (size_t)(col0 + rb + r16) * KD_STEP + k0 + swz * 8,
            &Bs[sel][rb * BK]);
  };

  // prologue: stage tiles 0,1 (6 instrs); wait tile 0 only
  stageAll(0, 0);
  stageAll(32, 1);
  asm volatile("s_waitcnt vmcnt(3)" ::: "memory");
  __builtin_amdgcn_sched_barrier(0);
  __builtin_amdgcn_s_barrier();
  __builtin_amdgcn_sched_barrier(0);

  constexpr int NT = KD_STEP / BK;   // 20
#pragma unroll
  for (int tt = 0; tt < NT; ++tt) {
    const int rd = tt % 3;
    // issue-early: tile t+2 staging (its buffer's readers done at barrier t-1)
    if (tt + 2 < NT) stageAll((tt + 2) * BK, (tt + 2) % 3);

    // fragment reads (phys chunk = q ^ (row&3), row&3 == L&3 here)
    const int pc = ((q ^ (L & 3)) * 8);
    bf16x8 af[4], bfv[4];
#pragma unroll
    for (int mt = 0; mt < 4; ++mt)
      af[mt] = *(const bf16x8*)&As[rd][(mrow + mt * 16 + (L & 15)) * BK + pc];
#pragma unroll
    for (int nt = 0; nt < 4; ++nt)
      bfv[nt] = *(const bf16x8*)&Bs[rd][(ncol + nt * 16 + (L & 15)) * BK + pc];

    __builtin_amdgcn_s_setprio(1);
#pragma unroll
    for (int mt = 0; mt < 4; ++mt)
#pragma unroll
      for (int nt = 0; nt < 4; ++nt)
        acc[mt][nt] = __builtin_amdgcn_mfma_f32_16x16x32_bf16(
            af[mt], bfv[nt], acc[mt][nt], 0, 0, 0);
    __builtin_amdgcn_s_setprio(0);

    // tile-end sync: counted vmcnt (leaves S(t+2) in flight) + ONE barrier
    if (tt < NT - 1) {
      if (tt + 2 < NT) asm volatile("s_waitcnt vmcnt(3)" ::: "memory");
      else             asm volatile("s_waitcnt vmcnt(0)" ::: "memory");
      __builtin_amdgcn_sched_barrier(0);
      __builtin_amdgcn_s_barrier();
      __builtin_amdgcn_sched_barrier(0);
    }
  }

  // epilogue: C/D layout col=lane&15, row=(lane>>4)*4+i
#pragma unroll
  for (int nt = 0; nt < 4; ++nt) {
    const int col = col0 + ncol + nt * 16 + (L & 15);
    const float bb = bias[col];
#pragma unroll
    for (int mt = 0; mt < 4; ++mt) {
#pragma unroll
      for (int i = 0; i < 4; ++i) {
        const int row = row0 + mrow + mt * 16 + q * 4 + i;
        outb[(size_t)row * NC_STEP + col] = f2bf(acc[mt][nt][i] + bb);
      }
    }
  }
}

// ---------------------------------------------------------------------------
// Embed GEMM (R0-proven single-buffer structure):
// tslice[f32] & tbf[bf16] = gather(Ebf, tokens) @ Lbf^T + lin_b
// ---------------------------------------------------------------------------
__global__ __launch_bounds__(256) void gemm_emb_k(
    const u16* __restrict__ Ebf, const int* __restrict__ tokd,
    const u16* __restrict__ Lbf, const float* __restrict__ bias,
    float* __restrict__ outf, u16* __restrict__ outb)
{
  __shared__ u16 As[128 * 64];
  __shared__ u16 Bs[128 * 64];
  const int t = threadIdx.x;
  const int w = t >> 6;
  const int L = t & 63;
  const int q = L >> 4;
  const int lrow8 = L >> 3;
  const int sub = L & 7;
  const int swz = sub ^ lrow8;
  const int row0 = blockIdx.x * 128;

  f32x4 acc[4][4];
#pragma unroll
  for (int a = 0; a < 4; ++a)
#pragma unroll
    for (int b = 0; b < 4; ++b)
      acc[a][b] = f32x4{0.f, 0.f, 0.f, 0.f};

  const int mrow = (w & 1) * 64;
  const int ncol = (w >> 1) * 64;

  int4 cidx[4];
#pragma unroll
  for (int jj = 0; jj < 4; ++jj) {
    const int rit = w * 32 + jj * 8 + lrow8;
    cidx[jj].x = tokd[(row0 + rit) * LTOK + 0];
    cidx[jj].y = tokd[(row0 + rit) * LTOK + 1];
    cidx[jj].z = tokd[(row0 + rit) * LTOK + 2];
    cidx[jj].w = 0;
  }

#pragma unroll
  for (int k0 = 0; k0 < KD_EMB; k0 += 64) {
    __syncthreads();
#pragma unroll
    for (int jj = 0; jj < 4; ++jj) {
      const int id = ((const int*)&cidx[jj])[k0 >> 7];
      const u16* base = Ebf + (size_t)id * HD;
      const int rit = w * 32 + jj * 8 + lrow8;
      async16(base + (k0 & 127) + swz * 8, &As[(w * 32 + jj * 8) * 64]);
      async16(Lbf + (size_t)rit * KD_EMB + k0 + swz * 8, &Bs[(w * 32 + jj * 8) * 64]);
    }
    __syncthreads();
#pragma unroll
    for (int ks = 0; ks < 2; ++ks) {
      bf16x8 af[4], bfr[4];
      const int pc = ((ks * 4 + q) ^ (L & 7)) * 8;
#pragma unroll
      for (int mt = 0; mt < 4; ++mt)
        af[mt] = *(const bf16x8*)&As[(mrow + mt * 16 + (L & 15)) * 64 + pc];
#pragma unroll
      for (int nt = 0; nt < 4; ++nt)
        bfr[nt] = *(const bf16x8*)&Bs[(ncol + nt * 16 + (L & 15)) * 64 + pc];
#pragma unroll
      for (int mt = 0; mt < 4; ++mt)
#pragma unroll
        for (int nt = 0; nt < 4; ++nt)
          acc[mt][nt] = __builtin_amdgcn_mfma_f32_16x16x32_bf16(af[mt], bfr[nt], acc[mt][nt], 0, 0, 0);
    }
  }

#pragma unroll
  for (int nt = 0; nt < 4; ++nt) {
    const int col = ncol + nt * 16 + (L & 15);
    const float bb = bias[col];
#pragma unroll
    for (int mt = 0; mt < 4; ++mt) {
#pragma unroll
      for (int i = 0; i < 4; ++i) {
        const int row = row0 + mrow + mt * 16 + q * 4 + i;
        const float v = acc[mt][nt][i] + bb;
        outf[(size_t)row * NC_EMB + col] = v;
        outb[(size_t)row * NC_EMB + col] = f2bf(v);
      }
    }
  }
}

// ---------------------------------------------------------------------------
// LSTM cell: f = sum_k sig(pre_fk)*c_k ; gates ; c (f32), h (bf16),
// t += h (f32) and bf16 shadow tbf.
// ---------------------------------------------------------------------------
__global__ __launch_bounds__(256) void cell_k(
    const u16* __restrict__ pre, const int* __restrict__ idxs,
    const float* __restrict__ c_prev, float* __restrict__ c_cur,
    u16* __restrict__ h_cur, float* __restrict__ t_io, u16* __restrict__ tbf)
{
  const int g = blockIdx.x * 256 + threadIdx.x;
  const int r = g >> 7;
  const int j = g & 127;
  const u16* pr = pre + (size_t)r * NC_STEP;
  float f = 0.f;
#pragma unroll
  for (int k = 0; k < KCH; ++k) {
    const int id = idxs[r * KCH + k];
    const float cg = (id >= 1) ? c_prev[(size_t)(id - 1) * HD + j] : 0.f;
    f += sigm(bf2f(pr[k * HD + j])) * cg;
  }
  const float iv = sigm(bf2f(pr[4 * HD + j]));
  const float uv = tanh_fast(bf2f(pr[5 * HD + j]));
  const float ov = sigm(bf2f(pr[6 * HD + j]));
  const float cn = iv * uv + f;
  const float hv = ov * tanh_fast(cn);
  c_cur[g] = cn;
  h_cur[g] = f2bf(hv);
  const float tn = t_io[g] + hv;
  t_io[g] = tn;
  tbf[g] = f2bf(tn);
}

__global__ __launch_bounds__(256) void conv_k(const float* __restrict__ src,
                                              u16* __restrict__ dst, int n4)
{
  const int g = blockIdx.x * 256 + threadIdx.x;
  if (g < n4) {
    float4 v = ((const float4*)src)[g];
    ((ushort4*)dst)[g] = make_ushort4(f2bf(v.x), f2bf(v.y), f2bf(v.z), f2bf(v.w));
  }
}

// Build U_big[l][896][640] (bf16) = [Uf;Uiuo | W_w(mapped)] + fused f32 biases.
__global__ __launch_bounds__(256) void prep_k(
    const float* __restrict__ Uf_w, const float* __restrict__ Uf_b,
    const float* __restrict__ Uiuo_w, const float* __restrict__ Uiuo_b,
    const float* __restrict__ W_w, const float* __restrict__ W_b,
    u16* __restrict__ Ubig, float* __restrict__ biasbig)
{
  const int l = blockIdx.y;
  const int e = blockIdx.x * 256 + threadIdx.x;
  const int c = e / KD_STEP;
  const int k = e % KD_STEP;
  float v;
  if (k < 512) {
    v = (c < 512) ? Uf_w[((size_t)l * 512 + c) * 512 + k]
                  : Uiuo_w[((size_t)l * 384 + (c - 512)) * 512 + k];
  } else {
    const int q = k - 512;
    const int wr = (c < 512) ? (c & 127) : (128 + (c - 512));
    v = W_w[((size_t)l * 512 + wr) * 128 + q];
  }
  Ubig[((size_t)l * 896 + c) * 640 + k] = f2bf(v);
  if (e < 896) {
    const float b = (e < 512)
        ? (Uf_b[l * 512 + e] + W_b[l * 512 + (e & 127)])
        : (Uiuo_b[l * 384 + (e - 512)] + W_b[l * 512 + 128 + (e - 512)]);
    biasbig[l * 896 + e] = b;
  }
}

// Output (FLOAT32): hx = tile(t_final,2), cx = tile(c_final,2).
__global__ __launch_bounds__(256) void fin_k(
    const float* __restrict__ t_fin, const float* __restrict__ c_fin,
    float* __restrict__ out)
{
  const size_t NH = (size_t)NNODE * HD;
  const size_t g = (size_t)blockIdx.x * 256 + threadIdx.x;
  const float h = t_fin[g];
  const float c = c_fin[g];
  out[g] = h;
  out[NH + g] = h;
  out[2 * NH + g] = c;
  out[3 * NH + g] = c;
}

extern "C" void kernel_launch(void* const* d_in, const int* in_sizes, int n_in,
                              void* d_out, int out_size, void* d_ws, size_t ws_size,
                              hipStream_t stream)
{
  (void)in_sizes; (void)n_in; (void)out_size; (void)ws_size;
  const int*   tokens  = (const int*)d_in[0];
  const int*   indices = (const int*)d_in[1];
  const float* E       = (const float*)d_in[2];
  const float* lin_w   = (const float*)d_in[3];
  const float* lin_b   = (const float*)d_in[4];
  const float* Uf_w    = (const float*)d_in[5];
  const float* Uf_b    = (const float*)d_in[6];
  const float* Uiuo_w  = (const float*)d_in[7];
  const float* Uiuo_b  = (const float*)d_in[8];
  const float* W_w     = (const float*)d_in[9];
  const float* W_b     = (const float*)d_in[10];
  float* out = (float*)d_out;   // FLOAT32 output (R8-proven)

  const size_t NH = (size_t)NNODE * HD;

  char* ws = (char*)d_ws;
  size_t off = 0;
  auto alloc = [&](size_t bytes) -> void* {
    void* p = ws + off;
    off = (off + bytes + 255) & ~(size_t)255;
    return p;
  };
  u16*   Ubig    = (u16*)alloc((size_t)2 * 896 * 640 * 2);
  float* biasbig = (float*)alloc(2 * 896 * 4);
  u16*   Ebf     = (u16*)alloc((size_t)50000 * HD * 2);
  u16*   Lbf     = (u16*)alloc((size_t)HD * KD_EMB * 2);
  float* tslice  = (float*)alloc(NH * 4);
  u16*   tbf     = (u16*)alloc(NH * 2);
  u16*   h0a     = (u16*)alloc(NH * 2);
  u16*   h0b     = (u16*)alloc(NH * 2);
  u16*   h1a     = (u16*)alloc(NH * 2);
  u16*   h1b     = (u16*)alloc(NH * 2);
  float* c0a     = (float*)alloc(NH * 4);
  float* c0b     = (float*)alloc(NH * 4);
  float* c1a     = (float*)alloc(NH * 4);
  float* c1b     = (float*)alloc(NH * 4);
  u16*   pre     = (u16*)alloc((size_t)NNODE * NC_STEP * 2);
  u16*   zbuf    = (u16*)alloc(512);

  u16*   h0[2] = {h0a, h0b};
  u16*   h1[2] = {h1a, h1b};
  float* c0[2] = {c0a, c0b};
  float* c1[2] = {c1a, c1b};

  hipMemsetAsync(zbuf, 0, 512, stream);
  hipMemsetAsync(h0[0], 0, NH * 2, stream);
  hipMemsetAsync(h1[0], 0, NH * 2, stream);
  hipMemsetAsync(c0[0], 0, NH * 4, stream);
  hipMemsetAsync(c1[0], 0, NH * 4, stream);
  prep_k<<<dim3(2240, 2), 256, 0, stream>>>(Uf_w, Uf_b, Uiuo_w, Uiuo_b, W_w, W_b,
                                            Ubig, biasbig);
  conv_k<<<dim3((50000 * HD / 4 + 255) / 256), 256, 0, stream>>>(E, Ebf, 50000 * HD / 4);
  conv_k<<<dim3((HD * KD_EMB / 4 + 255) / 256), 256, 0, stream>>>(lin_w, Lbf, HD * KD_EMB / 4);

  for (int d = 0; d < DD; ++d) {
    const int ri = d & 1, wi = (d + 1) & 1;
    const int* idxd = indices + (size_t)d * NNODE * KCH;
    const int* tokd = tokens + (size_t)d * NNODE * LTOK;

    // tslice (f32) + tbf (bf16) = gather(Ebf, tokens[d]) @ Lbf^T + lin_b
    gemm_emb_k<<<dim3(NNODE / 128), 256, 0, stream>>>(
        Ebf, tokd, Lbf, lin_b, tslice, tbf);

    for (int l = 0; l < 2; ++l) {
      const u16*   hp = (l == 0) ? h0[ri] : h1[ri];
      u16*         hc = (l == 0) ? h0[wi] : h1[wi];
      const float* cp = (l == 0) ? c0[ri] : c1[ri];
      float*       cc = (l == 0) ? c0[wi] : c1[wi];
      const u16* Ul = Ubig + (size_t)l * 896 * 640;
      const float* bl = biasbig + l * 896;
      gemm8_k<<<dim3((NNODE / BM) * (NC_STEP / BN)), 512, 0, stream>>>(
          hp, tbf, idxd, Ul, bl, pre, zbuf);
      cell_k<<<dim3((int)(NH / 256)), 256, 0, stream>>>(
          pre, idxd, cp, cc, hc, tslice, tbf);
    }
  }
  // after d=11: tslice = t_final, c1[0] = c_final
  fin_k<<<dim3((int)(NH / 256)), 256, 0, stream>>>(tslice, c1[0], out);
}

// Round 7
// 2138.977 us; speedup vs baseline: 1.2989x; 1.0060x over previous
//
#include <hip/hip_runtime.h>
#include <cstdint>
#include <cstddef>

#define DD 12
#define NNODE 32768
#define LTOK 3
#define KCH 4
#define HD 128
#define NC_STEP 896
#define KD_STEP 640
#define NC_EMB 128
#define KD_EMB 384

typedef unsigned short u16;
typedef __attribute__((ext_vector_type(8))) __bf16 bf16x8;
typedef __attribute__((ext_vector_type(4))) float f32x4;

__device__ __forceinline__ float bf2f(unsigned int u) {
  union { unsigned int i; float f; } v; v.i = (u & 0xffffu) << 16; return v.f;
}
__device__ __forceinline__ u16 f2bf(float f) {
  union { float f; unsigned int i; } v; v.f = f;
  unsigned int x = v.i;
  return (u16)((x + 0x7fffu + ((x >> 16) & 1u)) >> 16);
}
__device__ __forceinline__ float sigm(float x) { return 1.f / (1.f + __expf(-x)); }
__device__ __forceinline__ float tanh_fast(float x) { return 1.f - 2.f / (1.f + __expf(2.f * x)); }
__device__ __forceinline__ void async16(const void* g, void* l) {
  __builtin_amdgcn_global_load_lds((const __attribute__((address_space(1))) unsigned int*)g,
                                   (__attribute__((address_space(3))) unsigned int*)l, 16, 0, 0);
}

// ---------------------------------------------------------------------------
// R15 step GEMM: pre[32768,896] = A[32768,640] @ Ubig[896,640]^T + bias.
// = R6 (53.6 us, best) with ONE fix: the BK=32 swizzle.
// R6 post-mortem: chunk = q^(row&3) gave 4-way bank conflicts (4.59M/disp,
// ~14% of kernel): 64B rows span 16 banks -> bank base = 16*(row&1)+4*chunk;
// rows 0,4,8,12 of a q-group shared {0,20,8,28}. Correct swizzle must use
// row bits 2-3: phys slot s of row r holds global chunk s ^ ((r>>2)&3).
// Then a q-group's bases = {0,16,4,20,8,24,12,28} each x2 -> 2-way (free,
// m136), the same per-16-lane tiling as the BK=64 pattern that measured 0.
//   stage: lane L -> row L>>2, slot L&3 -> fetch global chunk (L&3)^((L>>4)&3)
//   read:  global chunk q at row (..+(L&15)) -> phys slot q ^ ((L>>2)&3)
// (mrow/mt*16/rbase are multiples of 16 -> drop out of (row>>2)&3.)
// Everything else frozen from R6:
// BM=256 x BN=128, BK=32, 512 thr / 8 waves (4M x 2N -> per-wave 64x64).
// 3-buffer LDS 72 KB -> 2 blocks/CU (cross-block TLP hides barrier convoy).
// Per K-tile per wave: 3 async16 stage (t+2), 8 ds_read_b128, 16 MFMA,
// belt vmcnt(3) (leaves S(t+2) in flight, never drain-to-0), ONE s_barrier.
// Grid: 1-D 896 = 8*112 bijective XCD chunk swizzle, col-tile fastest.
// ---------------------------------------------------------------------------
#define BM 256
#define BN 128
#define BK 32

__global__ __launch_bounds__(512, 4) void gemm8_k(
    const u16* __restrict__ Abf, const u16* __restrict__ Tbf,
    const int* __restrict__ gidx, const u16* __restrict__ B,
    const float* __restrict__ bias, u16* __restrict__ outb,
    const u16* __restrict__ zbuf)
{
  __shared__ u16 As[3][BM * BK];   // 3 x 16 KB
  __shared__ u16 Bs[3][BN * BK];   // 3 x 8 KB
  const int t = threadIdx.x;
  const int w = t >> 6;            // 0..7
  const int L = t & 63;
  const int q = L >> 4;            // 0..3 : k-chunk this lane's MFMA frag uses
  const int r16 = L >> 2;          // 0..15 : row within 16-row stage slab
  const int sub = L & 3;           // 16B landing slot within 64B row
  const int swz = sub ^ ((L >> 4) & 3);   // global chunk this lane fetches
                                          // (= sub ^ ((r16>>2)&3))

  // bijective chunked XCD swizzle: 896 = 8 * 112; col-tile fastest in chunk
  const int bid = blockIdx.x;
  const int wg = (bid & 7) * 112 + (bid >> 3);
  const int rt = wg / 7;
  const int ct = wg - rt * 7;
  const int row0 = rt * BM;
  const int col0 = ct * BN;

  const int wm = w >> 1;           // 0..3 : 64-row group
  const int wn = w & 1;            // 0..1 : 64-col group
  const int mrow = wm * 64;
  const int ncol = wn * 64;

  f32x4 acc[4][4];
#pragma unroll
  for (int a = 0; a < 4; ++a)
#pragma unroll
    for (int b = 0; b < 4; ++b)
      acc[a][b] = f32x4{0.f, 0.f, 0.f, 0.f};

  // gather indices: wave stages A rows w*32 + j*16 + r16, j=0,1
  int4 cidx[2];
#pragma unroll
  for (int j = 0; j < 2; ++j)
    cidx[j] = *(const int4*)&gidx[(row0 + w * 32 + j * 16 + r16) * KCH];

  // stage k-chunk [k0,k0+32) of tile into buffer sel: 2 A instrs + 1 B instr
  auto stageAll = [&](const int k0, const int sel) {
#pragma unroll
    for (int j = 0; j < 2; ++j) {
      const int rbase = w * 32 + j * 16;     // 16-row slab
      const u16* src;
      if (k0 < 4 * HD) {
        const int id = ((const int*)&cidx[j])[k0 >> 7];
        const u16* base = (id >= 1) ? (Abf + (size_t)(id - 1) * HD) : zbuf;
        src = base + (k0 & 127) + swz * 8;
      } else {
        src = Tbf + (size_t)(row0 + rbase + r16) * HD + (k0 - 4 * HD) + swz * 8;
      }
      async16(src, &As[sel][rbase * BK]);
    }
    const int rb = w * 16;                    // B: 16 rows per wave
    async16(B + (size_t)(col0 + rb + r16) * KD_STEP + k0 + swz * 8,
            &Bs[sel][rb * BK]);
  };

  // prologue: stage tiles 0,1 (6 instrs); wait tile 0 only
  stageAll(0, 0);
  stageAll(32, 1);
  asm volatile("s_waitcnt vmcnt(3)" ::: "memory");
  __builtin_amdgcn_sched_barrier(0);
  __builtin_amdgcn_s_barrier();
  __builtin_amdgcn_sched_barrier(0);

  constexpr int NT = KD_STEP / BK;   // 20
#pragma unroll
  for (int tt = 0; tt < NT; ++tt) {
    const int rd = tt % 3;
    // issue-early: tile t+2 staging (its buffer's readers done at barrier t-1)
    if (tt + 2 < NT) stageAll((tt + 2) * BK, (tt + 2) % 3);

    // fragment reads: phys slot = q ^ ((row>>2)&3), row bits from L&15
    const int pc = (q ^ ((L >> 2) & 3)) * 8;
    bf16x8 af[4], bfv[4];
#pragma unroll
    for (int mt = 0; mt < 4; ++mt)
      af[mt] = *(const bf16x8*)&As[rd][(mrow + mt * 16 + (L & 15)) * BK + pc];
#pragma unroll
    for (int nt = 0; nt < 4; ++nt)
      bfv[nt] = *(const bf16x8*)&Bs[rd][(ncol + nt * 16 + (L & 15)) * BK + pc];

    __builtin_amdgcn_s_setprio(1);
#pragma unroll
    for (int mt = 0; mt < 4; ++mt)
#pragma unroll
      for (int nt = 0; nt < 4; ++nt)
        acc[mt][nt] = __builtin_amdgcn_mfma_f32_16x16x32_bf16(
            af[mt], bfv[nt], acc[mt][nt], 0, 0, 0);
    __builtin_amdgcn_s_setprio(0);

    // tile-end sync: counted vmcnt (leaves S(t+2) in flight) + ONE barrier
    if (tt < NT - 1) {
      if (tt + 2 < NT) asm volatile("s_waitcnt vmcnt(3)" ::: "memory");
      else             asm volatile("s_waitcnt vmcnt(0)" ::: "memory");
      __builtin_amdgcn_sched_barrier(0);
      __builtin_amdgcn_s_barrier();
      __builtin_amdgcn_sched_barrier(0);
    }
  }

  // epilogue: C/D layout col=lane&15, row=(lane>>4)*4+i
#pragma unroll
  for (int nt = 0; nt < 4; ++nt) {
    const int col = col0 + ncol + nt * 16 + (L & 15);
    const float bb = bias[col];
#pragma unroll
    for (int mt = 0; mt < 4; ++mt) {
#pragma unroll
      for (int i = 0; i < 4; ++i) {
        const int row = row0 + mrow + mt * 16 + q * 4 + i;
        outb[(size_t)row * NC_STEP + col] = f2bf(acc[mt][nt][i] + bb);
      }
    }
  }
}

// ---------------------------------------------------------------------------
// Embed GEMM (R0-proven single-buffer structure):
// tslice[f32] & tbf[bf16] = gather(Ebf, tokens) @ Lbf^T + lin_b
// ---------------------------------------------------------------------------
__global__ __launch_bounds__(256) void gemm_emb_k(
    const u16* __restrict__ Ebf, const int* __restrict__ tokd,
    const u16* __restrict__ Lbf, const float* __restrict__ bias,
    float* __restrict__ outf, u16* __restrict__ outb)
{
  __shared__ u16 As[128 * 64];
  __shared__ u16 Bs[128 * 64];
  const int t = threadIdx.x;
  const int w = t >> 6;
  const int L = t & 63;
  const int q = L >> 4;
  const int lrow8 = L >> 3;
  const int sub = L & 7;
  const int swz = sub ^ lrow8;
  const int row0 = blockIdx.x * 128;

  f32x4 acc[4][4];
#pragma unroll
  for (int a = 0; a < 4; ++a)
#pragma unroll
    for (int b = 0; b < 4; ++b)
      acc[a][b] = f32x4{0.f, 0.f, 0.f, 0.f};

  const int mrow = (w & 1) * 64;
  const int ncol = (w >> 1) * 64;

  int4 cidx[4];
#pragma unroll
  for (int jj = 0; jj < 4; ++jj) {
    const int rit = w * 32 + jj * 8 + lrow8;
    cidx[jj].x = tokd[(row0 + rit) * LTOK + 0];
    cidx[jj].y = tokd[(row0 + rit) * LTOK + 1];
    cidx[jj].z = tokd[(row0 + rit) * LTOK + 2];
    cidx[jj].w = 0;
  }

#pragma unroll
  for (int k0 = 0; k0 < KD_EMB; k0 += 64) {
    __syncthreads();
#pragma unroll
    for (int jj = 0; jj < 4; ++jj) {
      const int id = ((const int*)&cidx[jj])[k0 >> 7];
      const u16* base = Ebf + (size_t)id * HD;
      const int rit = w * 32 + jj * 8 + lrow8;
      async16(base + (k0 & 127) + swz * 8, &As[(w * 32 + jj * 8) * 64]);
      async16(Lbf + (size_t)rit * KD_EMB + k0 + swz * 8, &Bs[(w * 32 + jj * 8) * 64]);
    }
    __syncthreads();
#pragma unroll
    for (int ks = 0; ks < 2; ++ks) {
      bf16x8 af[4], bfr[4];
      const int pc = ((ks * 4 + q) ^ (L & 7)) * 8;
#pragma unroll
      for (int mt = 0; mt < 4; ++mt)
        af[mt] = *(const bf16x8*)&As[(mrow + mt * 16 + (L & 15)) * 64 + pc];
#pragma unroll
      for (int nt = 0; nt < 4; ++nt)
        bfr[nt] = *(const bf16x8*)&Bs[(ncol + nt * 16 + (L & 15)) * 64 + pc];
#pragma unroll
      for (int mt = 0; mt < 4; ++mt)
#pragma unroll
        for (int nt = 0; nt < 4; ++nt)
          acc[mt][nt] = __builtin_amdgcn_mfma_f32_16x16x32_bf16(af[mt], bfr[nt], acc[mt][nt], 0, 0, 0);
    }
  }

#pragma unroll
  for (int nt = 0; nt < 4; ++nt) {
    const int col = ncol + nt * 16 + (L & 15);
    const float bb = bias[col];
#pragma unroll
    for (int mt = 0; mt < 4; ++mt) {
#pragma unroll
      for (int i = 0; i < 4; ++i) {
        const int row = row0 + mrow + mt * 16 + q * 4 + i;
        const float v = acc[mt][nt][i] + bb;
        outf[(size_t)row * NC_EMB + col] = v;
        outb[(size_t)row * NC_EMB + col] = f2bf(v);
      }
    }
  }
}

// ---------------------------------------------------------------------------
// LSTM cell: f = sum_k sig(pre_fk)*c_k ; gates ; c (f32), h (bf16),
// t += h (f32) and bf16 shadow tbf.
// ---------------------------------------------------------------------------
__global__ __launch_bounds__(256) void cell_k(
    const u16* __restrict__ pre, const int* __restrict__ idxs,
    const float* __restrict__ c_prev, float* __restrict__ c_cur,
    u16* __restrict__ h_cur, float* __restrict__ t_io, u16* __restrict__ tbf)
{
  const int g = blockIdx.x * 256 + threadIdx.x;
  const int r = g >> 7;
  const int j = g & 127;
  const u16* pr = pre + (size_t)r * NC_STEP;
  float f = 0.f;
#pragma unroll
  for (int k = 0; k < KCH; ++k) {
    const int id = idxs[r * KCH + k];
    const float cg = (id >= 1) ? c_prev[(size_t)(id - 1) * HD + j] : 0.f;
    f += sigm(bf2f(pr[k * HD + j])) * cg;
  }
  const float iv = sigm(bf2f(pr[4 * HD + j]));
  const float uv = tanh_fast(bf2f(pr[5 * HD + j]));
  const float ov = sigm(bf2f(pr[6 * HD + j]));
  const float cn = iv * uv + f;
  const float hv = ov * tanh_fast(cn);
  c_cur[g] = cn;
  h_cur[g] = f2bf(hv);
  const float tn = t_io[g] + hv;
  t_io[g] = tn;
  tbf[g] = f2bf(tn);
}

__global__ __launch_bounds__(256) void conv_k(const float* __restrict__ src,
                                              u16* __restrict__ dst, int n4)
{
  const int g = blockIdx.x * 256 + threadIdx.x;
  if (g < n4) {
    float4 v = ((const float4*)src)[g];
    ((ushort4*)dst)[g] = make_ushort4(f2bf(v.x), f2bf(v.y), f2bf(v.z), f2bf(v.w));
  }
}

// Build U_big[l][896][640] (bf16) = [Uf;Uiuo | W_w(mapped)] + fused f32 biases.
__global__ __launch_bounds__(256) void prep_k(
    const float* __restrict__ Uf_w, const float* __restrict__ Uf_b,
    const float* __restrict__ Uiuo_w, const float* __restrict__ Uiuo_b,
    const float* __restrict__ W_w, const float* __restrict__ W_b,
    u16* __restrict__ Ubig, float* __restrict__ biasbig)
{
  const int l = blockIdx.y;
  const int e = blockIdx.x * 256 + threadIdx.x;
  const int c = e / KD_STEP;
  const int k = e % KD_STEP;
  float v;
  if (k < 512) {
    v = (c < 512) ? Uf_w[((size_t)l * 512 + c) * 512 + k]
                  : Uiuo_w[((size_t)l * 384 + (c - 512)) * 512 + k];
  } else {
    const int q = k - 512;
    const int wr = (c < 512) ? (c & 127) : (128 + (c - 512));
    v = W_w[((size_t)l * 512 + wr) * 128 + q];
  }
  Ubig[((size_t)l * 896 + c) * 640 + k] = f2bf(v);
  if (e < 896) {
    const float b = (e < 512)
        ? (Uf_b[l * 512 + e] + W_b[l * 512 + (e & 127)])
        : (Uiuo_b[l * 384 + (e - 512)] + W_b[l * 512 + 128 + (e - 512)]);
    biasbig[l * 896 + e] = b;
  }
}

// Output (FLOAT32): hx = tile(t_final,2), cx = tile(c_final,2).
__global__ __launch_bounds__(256) void fin_k(
    const float* __restrict__ t_fin, const float* __restrict__ c_fin,
    float* __restrict__ out)
{
  const size_t NH = (size_t)NNODE * HD;
  const size_t g = (size_t)blockIdx.x * 256 + threadIdx.x;
  const float h = t_fin[g];
  const float c = c_fin[g];
  out[g] = h;
  out[NH + g] = h;
  out[2 * NH + g] = c;
  out[3 * NH + g] = c;
}

extern "C" void kernel_launch(void* const* d_in, const int* in_sizes, int n_in,
                              void* d_out, int out_size, void* d_ws, size_t ws_size,
                              hipStream_t stream)
{
  (void)in_sizes; (void)n_in; (void)out_size; (void)ws_size;
  const int*   tokens  = (const int*)d_in[0];
  const int*   indices = (const int*)d_in[1];
  const float* E       = (const float*)d_in[2];
  const float* lin_w   = (const float*)d_in[3];
  const float* lin_b   = (const float*)d_in[4];
  const float* Uf_w    = (const float*)d_in[5];
  const float* Uf_b    = (const float*)d_in[6];
  const float* Uiuo_w  = (const float*)d_in[7];
  const float* Uiuo_b  = (const float*)d_in[8];
  const float* W_w     = (const float*)d_in[9];
  const float* W_b     = (const float*)d_in[10];
  float* out = (float*)d_out;   // FLOAT32 output (R8-proven)

  const size_t NH = (size_t)NNODE * HD;

  char* ws = (char*)d_ws;
  size_t off = 0;
  auto alloc = [&](size_t bytes) -> void* {
    void* p = ws + off;
    off = (off + bytes + 255) & ~(size_t)255;
    return p;
  };
  u16*   Ubig    = (u16*)alloc((size_t)2 * 896 * 640 * 2);
  float* biasbig = (float*)alloc(2 * 896 * 4);
  u16*   Ebf     = (u16*)alloc((size_t)50000 * HD * 2);
  u16*   Lbf     = (u16*)alloc((size_t)HD * KD_EMB * 2);
  float* tslice  = (float*)alloc(NH * 4);
  u16*   tbf     = (u16*)alloc(NH * 2);
  u16*   h0a     = (u16*)alloc(NH * 2);
  u16*   h0b     = (u16*)alloc(NH * 2);
  u16*   h1a     = (u16*)alloc(NH * 2);
  u16*   h1b     = (u16*)alloc(NH * 2);
  float* c0a     = (float*)alloc(NH * 4);
  float* c0b     = (float*)alloc(NH * 4);
  float* c1a     = (float*)alloc(NH * 4);
  float* c1b     = (float*)alloc(NH * 4);
  u16*   pre     = (u16*)alloc((size_t)NNODE * NC_STEP * 2);
  u16*   zbuf    = (u16*)alloc(512);

  u16*   h0[2] = {h0a, h0b};
  u16*   h1[2] = {h1a, h1b};
  float* c0[2] = {c0a, c0b};
  float* c1[2] = {c1a, c1b};

  hipMemsetAsync(zbuf, 0, 512, stream);
  hipMemsetAsync(h0[0], 0, NH * 2, stream);
  hipMemsetAsync(h1[0], 0, NH * 2, stream);
  hipMemsetAsync(c0[0], 0, NH * 4, stream);
  hipMemsetAsync(c1[0], 0, NH * 4, stream);
  prep_k<<<dim3(2240, 2), 256, 0, stream>>>(Uf_w, Uf_b, Uiuo_w, Uiuo_b, W_w, W_b,
                                            Ubig, biasbig);
  conv_k<<<dim3((50000 * HD / 4 + 255) / 256), 256, 0, stream>>>(E, Ebf, 50000 * HD / 4);
  conv_k<<<dim3((HD * KD_EMB / 4 + 255) / 256), 256, 0, stream>>>(lin_w, Lbf, HD * KD_EMB / 4);

  for (int d = 0; d < DD; ++d) {
    const int ri = d & 1, wi = (d + 1) & 1;
    const int* idxd = indices + (size_t)d * NNODE * KCH;
    const int* tokd = tokens + (size_t)d * NNODE * LTOK;

    // tslice (f32) + tbf (bf16) = gather(Ebf, tokens[d]) @ Lbf^T + lin_b
    gemm_emb_k<<<dim3(NNODE / 128), 256, 0, stream>>>(
        Ebf, tokd, Lbf, lin_b, tslice, tbf);

    for (int l = 0; l < 2; ++l) {
      const u16*   hp = (l == 0) ? h0[ri] : h1[ri];
      u16*         hc = (l == 0) ? h0[wi] : h1[wi];
      const float* cp = (l == 0) ? c0[ri] : c1[ri];
      float*       cc = (l == 0) ? c0[wi] : c1[wi];
      const u16* Ul = Ubig + (size_t)l * 896 * 640;
      const float* bl = biasbig + l * 896;
      gemm8_k<<<dim3((NNODE / BM) * (NC_STEP / BN)), 512, 0, stream>>>(
          hp, tbf, idxd, Ul, bl, pre, zbuf);
      cell_k<<<dim3((int)(NH / 256)), 256, 0, stream>>>(
          pre, idxd, cp, cc, hc, tslice, tbf);
    }
  }
  // after d=11: tslice = t_final, c1[0] = c_final
  fin_k<<<dim3((int)(NH / 256)), 256, 0, stream>>>(tslice, c1[0], out);
}

// Round 8
// 2131.790 us; speedup vs baseline: 1.3033x; 1.0034x over previous
//
#include <hip/hip_runtime.h>
#include <cstdint>
#include <cstddef>

#define DD 12
#define NNODE 32768
#define LTOK 3
#define KCH 4
#define HD 128
#define NC_STEP 896
#define KD_STEP 640
#define NC_EMB 128
#define KD_EMB 384

typedef unsigned short u16;
typedef __attribute__((ext_vector_type(8))) __bf16 bf16x8;
typedef __attribute__((ext_vector_type(4))) float f32x4;

__device__ __forceinline__ float bf2f(unsigned int u) {
  union { unsigned int i; float f; } v; v.i = (u & 0xffffu) << 16; return v.f;
}
__device__ __forceinline__ u16 f2bf(float f) {
  union { float f; unsigned int i; } v; v.f = f;
  unsigned int x = v.i;
  return (u16)((x + 0x7fffu + ((x >> 16) & 1u)) >> 16);
}
__device__ __forceinline__ float sigm(float x) { return 1.f / (1.f + __expf(-x)); }
__device__ __forceinline__ float tanh_fast(float x) { return 1.f - 2.f / (1.f + __expf(2.f * x)); }
__device__ __forceinline__ void async16(const void* g, void* l) {
  __builtin_amdgcn_global_load_lds((const __attribute__((address_space(1))) unsigned int*)g,
                                   (__attribute__((address_space(3))) unsigned int*)l, 16, 0, 0);
}

// ---------------------------------------------------------------------------
// R16 step GEMM: pre[32768,896] = A[32768,640] @ Ubig[896,640]^T + bias.
// = R6/R7 (53.6 us) with the swizzle fixed at the RIGHT granularity.
// R7 post-mortem: conflict count bit-identical (4,587,520 = 4/ds_read_b128)
// across two different swizzles -> b128 is processed in 8-lane phases
// (8 x 16B = 128B = full bank width). Both old swizzles were 2-way WITHIN
// an 8-lane phase (rows of equal parity shared a bank quad). Conflict-free
// condition: across 8 consecutive rows, chunk must take all 4 values within
// each row-parity class -> chunk = s ^ ((r>>1)&3):
//   rows 0..7 -> chunks 0,0,1,1,2,2,3,3 -> banks 0-3,16-19,4-7,20-23,
//   8-11,24-27,12-15,28-31 = all 32 banks, 1 cyc/phase.
// (Also balanced at 16/32/64-lane granularity; matches the BK=64 pattern's
// zero-conflict principle: cover all bank quads per phase.)
//   stage: lane L -> row L>>2, slot L&3 -> fetch global chunk (L&3)^((L>>3)&3)
//   read:  global chunk q at row (..+(L&15)) -> phys slot q ^ ((L>>1)&3)
// Everything else frozen from R6 (best measured):
// BM=256 x BN=128, BK=32, 512 thr / 8 waves (4M x 2N -> per-wave 64x64).
// 3-buffer LDS 72 KB -> 2 blocks/CU (cross-block TLP hides barrier convoy).
// Per K-tile per wave: 3 async16 stage (t+2), 8 ds_read_b128, 16 MFMA,
// belt vmcnt(3) (leaves S(t+2) in flight, never drain-to-0), ONE s_barrier.
// Grid: 1-D 896 = 8*112 bijective XCD chunk swizzle, col-tile fastest.
// ---------------------------------------------------------------------------
#define BM 256
#define BN 128
#define BK 32

__global__ __launch_bounds__(512, 4) void gemm8_k(
    const u16* __restrict__ Abf, const u16* __restrict__ Tbf,
    const int* __restrict__ gidx, const u16* __restrict__ B,
    const float* __restrict__ bias, u16* __restrict__ outb,
    const u16* __restrict__ zbuf)
{
  __shared__ u16 As[3][BM * BK];   // 3 x 16 KB
  __shared__ u16 Bs[3][BN * BK];   // 3 x 8 KB
  const int t = threadIdx.x;
  const int w = t >> 6;            // 0..7
  const int L = t & 63;
  const int q = L >> 4;            // 0..3 : k-chunk this lane's MFMA frag uses
  const int r16 = L >> 2;          // 0..15 : row within 16-row stage slab
  const int sub = L & 3;           // 16B landing slot within 64B row
  const int swz = sub ^ ((L >> 3) & 3);   // global chunk this lane fetches
                                          // (= sub ^ ((row>>1)&3), row=L>>2)

  // bijective chunked XCD swizzle: 896 = 8 * 112; col-tile fastest in chunk
  const int bid = blockIdx.x;
  const int wg = (bid & 7) * 112 + (bid >> 3);
  const int rt = wg / 7;
  const int ct = wg - rt * 7;
  const int row0 = rt * BM;
  const int col0 = ct * BN;

  const int wm = w >> 1;           // 0..3 : 64-row group
  const int wn = w & 1;            // 0..1 : 64-col group
  const int mrow = wm * 64;
  const int ncol = wn * 64;

  f32x4 acc[4][4];
#pragma unroll
  for (int a = 0; a < 4; ++a)
#pragma unroll
    for (int b = 0; b < 4; ++b)
      acc[a][b] = f32x4{0.f, 0.f, 0.f, 0.f};

  // gather indices: wave stages A rows w*32 + j*16 + r16, j=0,1
  int4 cidx[2];
#pragma unroll
  for (int j = 0; j < 2; ++j)
    cidx[j] = *(const int4*)&gidx[(row0 + w * 32 + j * 16 + r16) * KCH];

  // stage k-chunk [k0,k0+32) of tile into buffer sel: 2 A instrs + 1 B instr
  auto stageAll = [&](const int k0, const int sel) {
#pragma unroll
    for (int j = 0; j < 2; ++j) {
      const int rbase = w * 32 + j * 16;     // 16-row slab
      const u16* src;
      if (k0 < 4 * HD) {
        const int id = ((const int*)&cidx[j])[k0 >> 7];
        const u16* base = (id >= 1) ? (Abf + (size_t)(id - 1) * HD) : zbuf;
        src = base + (k0 & 127) + swz * 8;
      } else {
        src = Tbf + (size_t)(row0 + rbase + r16) * HD + (k0 - 4 * HD) + swz * 8;
      }
      async16(src, &As[sel][rbase * BK]);
    }
    const int rb = w * 16;                    // B: 16 rows per wave
    async16(B + (size_t)(col0 + rb + r16) * KD_STEP + k0 + swz * 8,
            &Bs[sel][rb * BK]);
  };

  // prologue: stage tiles 0,1 (6 instrs); wait tile 0 only
  stageAll(0, 0);
  stageAll(32, 1);
  asm volatile("s_waitcnt vmcnt(3)" ::: "memory");
  __builtin_amdgcn_sched_barrier(0);
  __builtin_amdgcn_s_barrier();
  __builtin_amdgcn_sched_barrier(0);

  constexpr int NT = KD_STEP / BK;   // 20
#pragma unroll
  for (int tt = 0; tt < NT; ++tt) {
    const int rd = tt % 3;
    // issue-early: tile t+2 staging (its buffer's readers done at barrier t-1)
    if (tt + 2 < NT) stageAll((tt + 2) * BK, (tt + 2) % 3);

    // fragment reads: phys slot = q ^ ((row>>1)&3), row bits from L&15
    const int pc = (q ^ ((L >> 1) & 3)) * 8;
    bf16x8 af[4], bfv[4];
#pragma unroll
    for (int mt = 0; mt < 4; ++mt)
      af[mt] = *(const bf16x8*)&As[rd][(mrow + mt * 16 + (L & 15)) * BK + pc];
#pragma unroll
    for (int nt = 0; nt < 4; ++nt)
      bfv[nt] = *(const bf16x8*)&Bs[rd][(ncol + nt * 16 + (L & 15)) * BK + pc];

    __builtin_amdgcn_s_setprio(1);
#pragma unroll
    for (int mt = 0; mt < 4; ++mt)
#pragma unroll
      for (int nt = 0; nt < 4; ++nt)
        acc[mt][nt] = __builtin_amdgcn_mfma_f32_16x16x32_bf16(
            af[mt], bfv[nt], acc[mt][nt], 0, 0, 0);
    __builtin_amdgcn_s_setprio(0);

    // tile-end sync: counted vmcnt (leaves S(t+2) in flight) + ONE barrier
    if (tt < NT - 1) {
      if (tt + 2 < NT) asm volatile("s_waitcnt vmcnt(3)" ::: "memory");
      else             asm volatile("s_waitcnt vmcnt(0)" ::: "memory");
      __builtin_amdgcn_sched_barrier(0);
      __builtin_amdgcn_s_barrier();
      __builtin_amdgcn_sched_barrier(0);
    }
  }

  // epilogue: C/D layout col=lane&15, row=(lane>>4)*4+i
#pragma unroll
  for (int nt = 0; nt < 4; ++nt) {
    const int col = col0 + ncol + nt * 16 + (L & 15);
    const float bb = bias[col];
#pragma unroll
    for (int mt = 0; mt < 4; ++mt) {
#pragma unroll
      for (int i = 0; i < 4; ++i) {
        const int row = row0 + mrow + mt * 16 + q * 4 + i;
        outb[(size_t)row * NC_STEP + col] = f2bf(acc[mt][nt][i] + bb);
      }
    }
  }
}

// ---------------------------------------------------------------------------
// Embed GEMM (R0-proven single-buffer structure):
// tslice[f32] & tbf[bf16] = gather(Ebf, tokens) @ Lbf^T + lin_b
// ---------------------------------------------------------------------------
__global__ __launch_bounds__(256) void gemm_emb_k(
    const u16* __restrict__ Ebf, const int* __restrict__ tokd,
    const u16* __restrict__ Lbf, const float* __restrict__ bias,
    float* __restrict__ outf, u16* __restrict__ outb)
{
  __shared__ u16 As[128 * 64];
  __shared__ u16 Bs[128 * 64];
  const int t = threadIdx.x;
  const int w = t >> 6;
  const int L = t & 63;
  const int q = L >> 4;
  const int lrow8 = L >> 3;
  const int sub = L & 7;
  const int swz = sub ^ lrow8;
  const int row0 = blockIdx.x * 128;

  f32x4 acc[4][4];
#pragma unroll
  for (int a = 0; a < 4; ++a)
#pragma unroll
    for (int b = 0; b < 4; ++b)
      acc[a][b] = f32x4{0.f, 0.f, 0.f, 0.f};

  const int mrow = (w & 1) * 64;
  const int ncol = (w >> 1) * 64;

  int4 cidx[4];
#pragma unroll
  for (int jj = 0; jj < 4; ++jj) {
    const int rit = w * 32 + jj * 8 + lrow8;
    cidx[jj].x = tokd[(row0 + rit) * LTOK + 0];
    cidx[jj].y = tokd[(row0 + rit) * LTOK + 1];
    cidx[jj].z = tokd[(row0 + rit) * LTOK + 2];
    cidx[jj].w = 0;
  }

#pragma unroll
  for (int k0 = 0; k0 < KD_EMB; k0 += 64) {
    __syncthreads();
#pragma unroll
    for (int jj = 0; jj < 4; ++jj) {
      const int id = ((const int*)&cidx[jj])[k0 >> 7];
      const u16* base = Ebf + (size_t)id * HD;
      const int rit = w * 32 + jj * 8 + lrow8;
      async16(base + (k0 & 127) + swz * 8, &As[(w * 32 + jj * 8) * 64]);
      async16(Lbf + (size_t)rit * KD_EMB + k0 + swz * 8, &Bs[(w * 32 + jj * 8) * 64]);
    }
    __syncthreads();
#pragma unroll
    for (int ks = 0; ks < 2; ++ks) {
      bf16x8 af[4], bfr[4];
      const int pc = ((ks * 4 + q) ^ (L & 7)) * 8;
#pragma unroll
      for (int mt = 0; mt < 4; ++mt)
        af[mt] = *(const bf16x8*)&As[(mrow + mt * 16 + (L & 15)) * 64 + pc];
#pragma unroll
      for (int nt = 0; nt < 4; ++nt)
        bfr[nt] = *(const bf16x8*)&Bs[(ncol + nt * 16 + (L & 15)) * 64 + pc];
#pragma unroll
      for (int mt = 0; mt < 4; ++mt)
#pragma unroll
        for (int nt = 0; nt < 4; ++nt)
          acc[mt][nt] = __builtin_amdgcn_mfma_f32_16x16x32_bf16(af[mt], bfr[nt], acc[mt][nt], 0, 0, 0);
    }
  }

#pragma unroll
  for (int nt = 0; nt < 4; ++nt) {
    const int col = ncol + nt * 16 + (L & 15);
    const float bb = bias[col];
#pragma unroll
    for (int mt = 0; mt < 4; ++mt) {
#pragma unroll
      for (int i = 0; i < 4; ++i) {
        const int row = row0 + mrow + mt * 16 + q * 4 + i;
        const float v = acc[mt][nt][i] + bb;
        outf[(size_t)row * NC_EMB + col] = v;
        outb[(size_t)row * NC_EMB + col] = f2bf(v);
      }
    }
  }
}

// ---------------------------------------------------------------------------
// LSTM cell: f = sum_k sig(pre_fk)*c_k ; gates ; c (f32), h (bf16),
// t += h (f32) and bf16 shadow tbf.
// ---------------------------------------------------------------------------
__global__ __launch_bounds__(256) void cell_k(
    const u16* __restrict__ pre, const int* __restrict__ idxs,
    const float* __restrict__ c_prev, float* __restrict__ c_cur,
    u16* __restrict__ h_cur, float* __restrict__ t_io, u16* __restrict__ tbf)
{
  const int g = blockIdx.x * 256 + threadIdx.x;
  const int r = g >> 7;
  const int j = g & 127;
  const u16* pr = pre + (size_t)r * NC_STEP;
  float f = 0.f;
#pragma unroll
  for (int k = 0; k < KCH; ++k) {
    const int id = idxs[r * KCH + k];
    const float cg = (id >= 1) ? c_prev[(size_t)(id - 1) * HD + j] : 0.f;
    f += sigm(bf2f(pr[k * HD + j])) * cg;
  }
  const float iv = sigm(bf2f(pr[4 * HD + j]));
  const float uv = tanh_fast(bf2f(pr[5 * HD + j]));
  const float ov = sigm(bf2f(pr[6 * HD + j]));
  const float cn = iv * uv + f;
  const float hv = ov * tanh_fast(cn);
  c_cur[g] = cn;
  h_cur[g] = f2bf(hv);
  const float tn = t_io[g] + hv;
  t_io[g] = tn;
  tbf[g] = f2bf(tn);
}

__global__ __launch_bounds__(256) void conv_k(const float* __restrict__ src,
                                              u16* __restrict__ dst, int n4)
{
  const int g = blockIdx.x * 256 + threadIdx.x;
  if (g < n4) {
    float4 v = ((const float4*)src)[g];
    ((ushort4*)dst)[g] = make_ushort4(f2bf(v.x), f2bf(v.y), f2bf(v.z), f2bf(v.w));
  }
}

// Build U_big[l][896][640] (bf16) = [Uf;Uiuo | W_w(mapped)] + fused f32 biases.
__global__ __launch_bounds__(256) void prep_k(
    const float* __restrict__ Uf_w, const float* __restrict__ Uf_b,
    const float* __restrict__ Uiuo_w, const float* __restrict__ Uiuo_b,
    const float* __restrict__ W_w, const float* __restrict__ W_b,
    u16* __restrict__ Ubig, float* __restrict__ biasbig)
{
  const int l = blockIdx.y;
  const int e = blockIdx.x * 256 + threadIdx.x;
  const int c = e / KD_STEP;
  const int k = e % KD_STEP;
  float v;
  if (k < 512) {
    v = (c < 512) ? Uf_w[((size_t)l * 512 + c) * 512 + k]
                  : Uiuo_w[((size_t)l * 384 + (c - 512)) * 512 + k];
  } else {
    const int q = k - 512;
    const int wr = (c < 512) ? (c & 127) : (128 + (c - 512));
    v = W_w[((size_t)l * 512 + wr) * 128 + q];
  }
  Ubig[((size_t)l * 896 + c) * 640 + k] = f2bf(v);
  if (e < 896) {
    const float b = (e < 512)
        ? (Uf_b[l * 512 + e] + W_b[l * 512 + (e & 127)])
        : (Uiuo_b[l * 384 + (e - 512)] + W_b[l * 512 + 128 + (e - 512)]);
    biasbig[l * 896 + e] = b;
  }
}

// Output (FLOAT32): hx = tile(t_final,2), cx = tile(c_final,2).
__global__ __launch_bounds__(256) void fin_k(
    const float* __restrict__ t_fin, const float* __restrict__ c_fin,
    float* __restrict__ out)
{
  const size_t NH = (size_t)NNODE * HD;
  const size_t g = (size_t)blockIdx.x * 256 + threadIdx.x;
  const float h = t_fin[g];
  const float c = c_fin[g];
  out[g] = h;
  out[NH + g] = h;
  out[2 * NH + g] = c;
  out[3 * NH + g] = c;
}

extern "C" void kernel_launch(void* const* d_in, const int* in_sizes, int n_in,
                              void* d_out, int out_size, void* d_ws, size_t ws_size,
                              hipStream_t stream)
{
  (void)in_sizes; (void)n_in; (void)out_size; (void)ws_size;
  const int*   tokens  = (const int*)d_in[0];
  const int*   indices = (const int*)d_in[1];
  const float* E       = (const float*)d_in[2];
  const float* lin_w   = (const float*)d_in[3];
  const float* lin_b   = (const float*)d_in[4];
  const float* Uf_w    = (const float*)d_in[5];
  const float* Uf_b    = (const float*)d_in[6];
  const float* Uiuo_w  = (const float*)d_in[7];
  const float* Uiuo_b  = (const float*)d_in[8];
  const float* W_w     = (const float*)d_in[9];
  const float* W_b     = (const float*)d_in[10];
  float* out = (float*)d_out;   // FLOAT32 output (R8-proven)

  const size_t NH = (size_t)NNODE * HD;

  char* ws = (char*)d_ws;
  size_t off = 0;
  auto alloc = [&](size_t bytes) -> void* {
    void* p = ws + off;
    off = (off + bytes + 255) & ~(size_t)255;
    return p;
  };
  u16*   Ubig    = (u16*)alloc((size_t)2 * 896 * 640 * 2);
  float* biasbig = (float*)alloc(2 * 896 * 4);
  u16*   Ebf     = (u16*)alloc((size_t)50000 * HD * 2);
  u16*   Lbf     = (u16*)alloc((size_t)HD * KD_EMB * 2);
  float* tslice  = (float*)alloc(NH * 4);
  u16*   tbf     = (u16*)alloc(NH * 2);
  u16*   h0a     = (u16*)alloc(NH * 2);
  u16*   h0b     = (u16*)alloc(NH * 2);
  u16*   h1a     = (u16*)alloc(NH * 2);
  u16*   h1b     = (u16*)alloc(NH * 2);
  float* c0a     = (float*)alloc(NH * 4);
  float* c0b     = (float*)alloc(NH * 4);
  float* c1a     = (float*)alloc(NH * 4);
  float* c1b     = (float*)alloc(NH * 4);
  u16*   pre     = (u16*)alloc((size_t)NNODE * NC_STEP * 2);
  u16*   zbuf    = (u16*)alloc(512);

  u16*   h0[2] = {h0a, h0b};
  u16*   h1[2] = {h1a, h1b};
  float* c0[2] = {c0a, c0b};
  float* c1[2] = {c1a, c1b};

  hipMemsetAsync(zbuf, 0, 512, stream);
  hipMemsetAsync(h0[0], 0, NH * 2, stream);
  hipMemsetAsync(h1[0], 0, NH * 2, stream);
  hipMemsetAsync(c0[0], 0, NH * 4, stream);
  hipMemsetAsync(c1[0], 0, NH * 4, stream);
  prep_k<<<dim3(2240, 2), 256, 0, stream>>>(Uf_w, Uf_b, Uiuo_w, Uiuo_b, W_w, W_b,
                                            Ubig, biasbig);
  conv_k<<<dim3((50000 * HD / 4 + 255) / 256), 256, 0, stream>>>(E, Ebf, 50000 * HD / 4);
  conv_k<<<dim3((HD * KD_EMB / 4 + 255) / 256), 256, 0, stream>>>(lin_w, Lbf, HD * KD_EMB / 4);

  for (int d = 0; d < DD; ++d) {
    const int ri = d & 1, wi = (d + 1) & 1;
    const int* idxd = indices + (size_t)d * NNODE * KCH;
    const int* tokd = tokens + (size_t)d * NNODE * LTOK;

    // tslice (f32) + tbf (bf16) = gather(Ebf, tokens[d]) @ Lbf^T + lin_b
    gemm_emb_k<<<dim3(NNODE / 128), 256, 0, stream>>>(
        Ebf, tokd, Lbf, lin_b, tslice, tbf);

    for (int l = 0; l < 2; ++l) {
      const u16*   hp = (l == 0) ? h0[ri] : h1[ri];
      u16*         hc = (l == 0) ? h0[wi] : h1[wi];
      const float* cp = (l == 0) ? c0[ri] : c1[ri];
      float*       cc = (l == 0) ? c0[wi] : c1[wi];
      const u16* Ul = Ubig + (size_t)l * 896 * 640;
      const float* bl = biasbig + l * 896;
      gemm8_k<<<dim3((NNODE / BM) * (NC_STEP / BN)), 512, 0, stream>>>(
          hp, tbf, idxd, Ul, bl, pre, zbuf);
      cell_k<<<dim3((int)(NH / 256)), 256, 0, stream>>>(
          pre, idxd, cp, cc, hc, tslice, tbf);
    }
  }
  // after d=11: tslice = t_final, c1[0] = c_final
  fin_k<<<dim3((int)(NH / 256)), 256, 0, stream>>>(tslice, c1[0], out);
}